// Round 12
// baseline (80.834 us; speedup 1.0000x reference)
//
#include <hip/hip_runtime.h>
#include <math.h>

#define B_ 8
#define C_ 3
#define HW_ 512
#define P_ 128
#define S_ 64
#define K_ 31
#define NZ_ 15
#define HID_ 64
#define NPOS_ 49   // 7x7 patch positions
#define BN_ (B_*NPOS_)

#define LSTRIDE_ 192   // bf16 elems/row; 384 B = 24 x 16B blocks == 0 mod 8 -> XOR swizzle applies
#define LROWB_ 384     // bytes per row
#define TROWS_ 96      // 64-row half + 31 halo + 1 spare
#define FRAG_U32_ 256  // one B fragment = 64 lanes x 16 B = 256 uints
#define NSTEP_ 16      // 16 row-pair steps; jrow = 2s + (k>=16), jrow=0 masked (halo-16)
#define BPOS_U32_ (NSTEP_ * 3 * FRAG_U32_)  // 12288 uints per patch position

typedef __attribute__((ext_vector_type(8))) short bf16x8;
typedef __attribute__((ext_vector_type(4))) float f32x4;

__device__ __forceinline__ float hann128(int p) {
    return 0.5f - 0.5f * cosf(6.283185307179586f * (float)p / 128.0f);
}

__device__ __forceinline__ unsigned int bf16_rne(float f) {
    union { float f; unsigned int u; } v; v.f = f;
    unsigned int r = v.u + 0x7fffu + ((v.u >> 16) & 1u);
    return r >> 16;
}

__device__ __forceinline__ float bf16_to_f(unsigned int bits16) {
    union { unsigned int u; float f; } v; v.u = bits16 << 16;
    return v.f;
}

// ---------------------------------------------------------------------------
// Kernel 1: MLP + pupil + 31x31 DFT -> normalized flipped kernel -> row-pair
// B-fragment precompute (halo-16 convention). One block per position (49).
// Fragment (s, c), logical k in [0,32): jrow = 2s + (k>=16),
//   B_c[k][n] = kf[jrow-1, 16c + (k&15) - n - 1] if jrow,tap in 1..31 else 0.
// Lane labeling (matches conv A reads, empirically validated r4-r11):
//   lane l: n = l&15, k = (l>>4)*8 + e, e = 0..7.
// ---------------------------------------------------------------------------
__global__ __launch_bounds__(1024) void psf_kernel(
    const float* __restrict__ w1, const float* __restrict__ b1,
    const float* __restrict__ w2, const float* __restrict__ b2,
    const float* __restrict__ w3, const float* __restrict__ b3,
    const float* __restrict__ basis, unsigned int* __restrict__ bfrags)
{
    __shared__ float h1[HID_], h2[HID_], coef[NZ_];
    __shared__ float pupR[961], pupI[961], tR[961], tI[961];
    __shared__ float rootR[31], rootI[31];
    __shared__ float red[16];
    int n = blockIdx.x;
    int nh = n / 7, nw = n % 7;
    int tid = threadIdx.x;
    float cy = (float)(nh * S_ + P_ / 2) * (2.0f / (float)HW_) - 1.0f;
    float cx = (float)(nw * S_ + P_ / 2) * (2.0f / (float)HW_) - 1.0f;

    if (tid < HID_) h1[tid] = fmaxf(0.0f, cy * w1[tid] + cx * w1[HID_ + tid] + b1[tid]);
    if (tid < 31) {
        float ang = -6.283185307179586f * (float)tid / 31.0f;
        rootR[tid] = cosf(ang);
        rootI[tid] = sinf(ang);
    }
    __syncthreads();
    if (tid < HID_) {
        float s = b2[tid];
        for (int k = 0; k < HID_; ++k) s = fmaf(h1[k], w2[k * HID_ + tid], s);
        h2[tid] = fmaxf(0.0f, s);
    }
    __syncthreads();
    if (tid < NZ_) {
        float s = b3[tid];
        for (int k = 0; k < HID_; ++k) s = fmaf(h2[k], w3[k * NZ_ + tid], s);
        coef[tid] = s;
    }
    __syncthreads();

    for (int idx = tid; idx < 961; idx += 1024) {
        int h = idx / 31, w = idx % 31;
        float ph = 0.0f;
        for (int z = 0; z < NZ_; ++z) ph = fmaf(coef[z], basis[z * 961 + idx], ph);
        int dh = h - 15, dw = w - 15;
        bool m = (dh * dh + dw * dw) <= 225;
        float sv, cv;
        sincosf(ph, &sv, &cv);
        pupR[idx] = m ? cv : 0.0f;
        pupI[idx] = m ? sv : 0.0f;
    }
    __syncthreads();

    for (int idx = tid; idx < 961; idx += 1024) {
        int h = idx / 31, k = idx % 31;
        float ar = 0.0f, ai = 0.0f;
        for (int w = 0; w < 31; ++w) {
            int tt = (k * w) % 31;
            float cr = rootR[tt], ci = rootI[tt];
            float pr = pupR[h * 31 + w], pi = pupI[h * 31 + w];
            ar += pr * cr - pi * ci;
            ai += pr * ci + pi * cr;
        }
        tR[idx] = ar; tI[idx] = ai;
    }
    __syncthreads();

    float lsum = 0.0f;
    for (int idx = tid; idx < 961; idx += 1024) {
        int u = idx / 31, k = idx % 31;
        float gr = 0.0f, gi = 0.0f;
        for (int h = 0; h < 31; ++h) {
            int tt = (u * h) % 31;
            float cr = rootR[tt], ci = rootI[tt];
            float ar = tR[h * 31 + k], ai = tI[h * 31 + k];
            gr += ar * cr - ai * ci;
            gi += ar * ci + ai * cr;
        }
        float p = gr * gr + gi * gi;
        pupR[idx] = p;
        lsum += p;
    }
    float v = lsum;
    #pragma unroll
    for (int off = 32; off >= 1; off >>= 1) v += __shfl_xor(v, off, 64);
    if ((tid & 63) == 0) red[tid >> 6] = v;
    __syncthreads();
    if (tid == 0) {
        float s = 0.0f;
        #pragma unroll
        for (int i = 0; i < 16; ++i) s += red[i];
        red[0] = 1.0f / (s + 1e-12f);
    }
    __syncthreads();
    float inv = red[0];
    // kf[j,i] = psf_un[(15-j)%31, (15-i)%31] * inv  -> stash in tI (free now)
    for (int idx = tid; idx < 961; idx += 1024) {
        int j = idx / 31, i = idx % 31;
        int u = (15 - j + 31) % 31, vv = (15 - i + 31) % 31;
        tI[idx] = pupR[u * 31 + vv] * inv;
    }
    __syncthreads();

    unsigned int* bf = bfrags + (size_t)n * BPOS_U32_;
    for (int w2 = tid; w2 < BPOS_U32_; w2 += 1024) {
        int jc = w2 >> 8;            // 256 uints per fragment; jc = s*3 + c
        int s = jc / 3, c = jc % 3;
        int rem = w2 & 255;
        int l = rem >> 2, ew = rem & 3;
        int nn = l & 15, kg = l >> 4;
        unsigned int pack = 0;
        #pragma unroll
        for (int q = 0; q < 2; ++q) {
            int e = ew * 2 + q;
            int kk = kg * 8 + e;
            int jrow = 2 * s + (kk >> 4);          // halo-16: kernel row = jrow-1
            int tap = 16 * c + (kk & 15) - nn;     // halo-16: kernel col = tap-1
            float vx = (jrow >= 1 && jrow <= 31 && tap >= 1 && tap <= 31)
                       ? tI[(jrow - 1) * 31 + (tap - 1)] : 0.0f;
            pack |= bf16_rne(vx) << (16 * q);
        }
        bf[w2] = pack;
    }
}

// ---------------------------------------------------------------------------
// Kernel 2 (v12): row-pair banded bf16 MFMA GEMM + T2 XOR-swizzled LDS.
// One block per (patch, channel, row-half): 64x128 out, 512 threads = 8 waves
// (4 row-strips x 2 col-halves). LDS tile 96 rows x 384 B (stride == 0 mod
// 128B); physical byte = logical ^ ((row&7)<<4), applied at BOTH staging
// write and A-read -> aligned-8 lanes (8 consecutive rows, same col) hit all
// 8 bank groups bijectively. 36.9 KB -> 4 blocks/CU.
// ---------------------------------------------------------------------------
template<int MODE>
__global__ __launch_bounds__(512, 4) void conv_mfma_kernel(
    const float* __restrict__ x, const unsigned int* __restrict__ bfrags,
    void* __restrict__ dst)
{
    __shared__ unsigned short sIn[TROWS_ * LSTRIDE_];   // 96*384 = 36864 B
    __shared__ float sH[128];

    int t = blockIdx.x;
    int half = t & 1;
    int cc = (t >> 1) % 3;
    int bn = t / 6;
    int b = bn / NPOS_, n = bn % NPOS_;
    int nh = n / 7, nw = n % 7;
    int r0 = nh * S_, c0 = nw * S_;
    int tid = threadIdx.x;

    if (tid < 128) sH[tid] = hann128(tid);

    // zero-fill tile (halo + spare cols + invalid rows stay zero)
    for (int i = tid; i < TROWS_ * LROWB_ / 16; i += 512)
        ((uint4*)sIn)[i] = make_uint4(0u, 0u, 0u, 0u);
    __syncthreads();

    // stage interior with swizzled uint4 writes:
    // tile row r <-> patch row half*64 + r - 16; tile col 16+c8.. <-> patch col c8..
    const float* xb = x + ((size_t)(b * C_ + cc) * HW_ + r0) * HW_ + c0;
    int rpbase = half * 64 - 16;
    for (int i = tid; i < TROWS_ * 16; i += 512) {
        int r = i >> 4, c8 = (i & 15) * 8;   // patch cols c8..c8+7
        int rp = rpbase + r;
        if (rp >= 0 && rp < P_) {
            float4 v0 = *(const float4*)&xb[rp * HW_ + c8];
            float4 v1 = *(const float4*)&xb[rp * HW_ + c8 + 4];
            uint4 o;
            o.x = bf16_rne(v0.x) | (bf16_rne(v0.y) << 16);
            o.y = bf16_rne(v0.z) | (bf16_rne(v0.w) << 16);
            o.z = bf16_rne(v1.x) | (bf16_rne(v1.y) << 16);
            o.w = bf16_rne(v1.z) | (bf16_rne(v1.w) << 16);
            int byteoff = (r * LROWB_ + 32 + c8 * 2) ^ ((r & 7) << 4);
            *(uint4*)((char*)sIn + byteoff) = o;
        }
    }
    __syncthreads();

    int lane = tid & 63, wv = tid >> 6;
    int m0 = (wv & 3) * 16;        // row strip within the 64-row half
    int ch = (wv >> 2) * 64;       // col half
    int lrow = lane & 15, lkg = lane >> 4;

    f32x4 acc[4];
    #pragma unroll
    for (int q = 0; q < 4; ++q) acc[q] = (f32x4){0.f, 0.f, 0.f, 0.f};

    int rowb = m0 + lrow + (lkg >> 1);               // A row at step 0
    int colb = ch * 2 + (lkg & 1) * 16;              // byte col offset
    int xr[4];                                        // per-step XOR (period 4)
    #pragma unroll
    for (int sm = 0; sm < 4; ++sm) xr[sm] = ((rowb + 2 * sm) & 7) << 4;
    const bf16x8* bpos = (const bf16x8*)(bfrags + (size_t)n * BPOS_U32_) + lane;

    bf16x8 A0[6], A1[6], B0[3], B1[3];

#define LOADA(DST, S) { int base_ = (rowb + 2 * (S)) * LROWB_ + colb; int x_ = xr[(S) & 3]; \
    _Pragma("unroll") for (int p_ = 0; p_ < 6; ++p_) \
        DST[p_] = *(const bf16x8*)((const char*)sIn + ((base_ + p_ * 32) ^ x_)); }
#define LOADB(DST, S) { const bf16x8* bp_ = bpos + (S) * 192; \
    DST[0] = bp_[0]; DST[1] = bp_[64]; DST[2] = bp_[128]; }
#define DOMFMA(AA, BB) { _Pragma("unroll") for (int q_ = 0; q_ < 4; ++q_) { \
    acc[q_] = __builtin_amdgcn_mfma_f32_16x16x32_bf16(AA[q_],     BB[0], acc[q_], 0, 0, 0); \
    acc[q_] = __builtin_amdgcn_mfma_f32_16x16x32_bf16(AA[q_ + 1], BB[1], acc[q_], 0, 0, 0); \
    acc[q_] = __builtin_amdgcn_mfma_f32_16x16x32_bf16(AA[q_ + 2], BB[2], acc[q_], 0, 0, 0); } }

    LOADA(A0, 0); LOADB(B0, 0);

    #pragma unroll
    for (int s2 = 0; s2 < 8; ++s2) {
        LOADA(A1, 2 * s2 + 1); LOADB(B1, 2 * s2 + 1);
        __builtin_amdgcn_sched_barrier(0);
        __builtin_amdgcn_s_setprio(1);
        DOMFMA(A0, B0);
        __builtin_amdgcn_s_setprio(0);
        __builtin_amdgcn_sched_barrier(0);
        if (s2 < 7) { LOADA(A0, 2 * s2 + 2); LOADB(B0, 2 * s2 + 2); }
        __builtin_amdgcn_sched_barrier(0);
        __builtin_amdgcn_s_setprio(1);
        DOMFMA(A1, B1);
        __builtin_amdgcn_s_setprio(0);
        __builtin_amdgcn_sched_barrier(0);
    }
#undef LOADA
#undef LOADB
#undef DOMFMA

    // epilogue: C/D layout col = lane&15, row = lkg*4 + r (m89-verified)
    int prow0 = half * 64 + m0 + lkg * 4;
    float hy[4];
    #pragma unroll
    for (int r = 0; r < 4; ++r) hy[r] = sH[prow0 + r];

    #pragma unroll
    for (int q = 0; q < 4; ++q) {
        int pcol = ch + 16 * q + lrow;
        float hxv = sH[pcol];
        #pragma unroll
        for (int r = 0; r < 4; ++r) {
            int prow = prow0 + r;
            float val = acc[q][r] * hy[r] * hxv;
            if (MODE == 0) {
                unsigned short* yp = (unsigned short*)dst + (((size_t)bn * C_ + cc) << 14);
                yp[prow * P_ + pcol] = (unsigned short)bf16_rne(val);
            } else {
                float* ob = (float*)dst;
                atomicAdd(ob + ((size_t)(b * C_ + cc) * HW_ + r0 + prow) * HW_ + c0 + pcol, val);
            }
        }
    }
}

// ---------------------------------------------------------------------------
// Kernel 3a: gather overlap-add (x4 vectorized, bf16 patches), analytic divide
// ---------------------------------------------------------------------------
__global__ __launch_bounds__(256) void gather_kernel(
    const unsigned short* __restrict__ ypatch, float* __restrict__ out)
{
    __shared__ float sH[128];
    int tid = threadIdx.x;
    if (tid < 128) sH[tid] = hann128(tid);
    __syncthreads();

    int gid = blockIdx.x * 256 + tid;
    int base = gid * 4;
    if (base >= B_ * C_ * HW_ * HW_) return;
    int X = base & 511;
    int Y = (base >> 9) & 511;
    int bc = base >> 18;
    int c = bc % 3, b = bc / 3;
    int nhA = Y >> 6, pyA = Y & 63;
    int nwA = X >> 6, pxA = X & 63;       // multiple of 4
    bool vA = nhA <= 6, vB = nhA >= 1;
    bool uA = nwA <= 6, uB = nwA >= 1;
    float wy = (vA ? sH[pyA] : 0.0f) + (vB ? sH[pyA + 64] : 0.0f);

    float4 acc = {0.f, 0.f, 0.f, 0.f};
    #pragma unroll
    for (int sy = 0; sy < 2; ++sy) {
        bool okY = sy == 0 ? vA : vB;
        int nh = sy == 0 ? nhA : nhA - 1;
        int py = sy == 0 ? pyA : pyA + 64;
        #pragma unroll
        for (int sx = 0; sx < 2; ++sx) {
            bool okX = sx == 0 ? uA : uB;
            int nw = sx == 0 ? nwA : nwA - 1;
            int px = sx == 0 ? pxA : pxA + 64;
            if (okY && okX) {
                size_t off = ((((size_t)b * NPOS_ + nh * 7 + nw) * C_ + c) << 14) + (py << 7) + px;
                uint2 v = *(const uint2*)&ypatch[off];
                acc.x += bf16_to_f(v.x & 0xffffu);
                acc.y += bf16_to_f(v.x >> 16);
                acc.z += bf16_to_f(v.y & 0xffffu);
                acc.w += bf16_to_f(v.y >> 16);
            }
        }
    }
    float4 o;
    float wx0 = (uA ? sH[pxA + 0] : 0.0f) + (uB ? sH[pxA + 64] : 0.0f);
    float wx1 = (uA ? sH[pxA + 1] : 0.0f) + (uB ? sH[pxA + 65] : 0.0f);
    float wx2 = (uA ? sH[pxA + 2] : 0.0f) + (uB ? sH[pxA + 66] : 0.0f);
    float wx3 = (uA ? sH[pxA + 3] : 0.0f) + (uB ? sH[pxA + 67] : 0.0f);
    o.x = acc.x / (wy * wx0 + 1e-8f);
    o.y = acc.y / (wy * wx1 + 1e-8f);
    o.z = acc.z / (wy * wx2 + 1e-8f);
    o.w = acc.w / (wy * wx3 + 1e-8f);
    *(float4*)&out[base] = o;
}

// ---------------------------------------------------------------------------
// Kernel 3b: in-place divide (atomic fallback path)
// ---------------------------------------------------------------------------
__global__ __launch_bounds__(256) void divide_kernel(float* __restrict__ out)
{
    int idx = blockIdx.x * 256 + threadIdx.x;
    if (idx >= B_ * C_ * HW_ * HW_) return;
    int X = idx & 511;
    int Y = (idx >> 9) & 511;
    int nhA = Y >> 6, pyA = Y & 63;
    int nwA = X >> 6, pxA = X & 63;
    float wy = (nhA <= 6 ? hann128(pyA) : 0.0f) + (nhA >= 1 ? hann128(pyA + 64) : 0.0f);
    float wx = (nwA <= 6 ? hann128(pxA) : 0.0f) + (nwA >= 1 ? hann128(pxA + 64) : 0.0f);
    out[idx] = out[idx] / (wy * wx + 1e-8f);
}

extern "C" void kernel_launch(void* const* d_in, const int* in_sizes, int n_in,
                              void* d_out, int out_size, void* d_ws, size_t ws_size,
                              hipStream_t stream)
{
    const float* x    = (const float*)d_in[0];
    const float* w1   = (const float*)d_in[1];
    const float* b1   = (const float*)d_in[2];
    const float* w2   = (const float*)d_in[3];
    const float* b2   = (const float*)d_in[4];
    const float* w3   = (const float*)d_in[5];
    const float* b3   = (const float*)d_in[6];
    const float* basis = (const float*)d_in[7];
    float* out = (float*)d_out;

    unsigned int* bfrags = (unsigned int*)d_ws;
    size_t bfBytes = (size_t)NPOS_ * BPOS_U32_ * sizeof(unsigned int);            // ~2.41 MB
    size_t need = bfBytes + (size_t)BN_ * C_ * P_ * P_ * sizeof(unsigned short);  // + 38.5 MB

    psf_kernel<<<NPOS_, 1024, 0, stream>>>(w1, b1, w2, b2, w3, b3, basis, bfrags);

    int nPix = B_ * C_ * HW_ * HW_;
    if (ws_size >= need) {
        unsigned short* ypatch = (unsigned short*)((char*)d_ws + bfBytes);
        conv_mfma_kernel<0><<<BN_ * C_ * 2, 512, 0, stream>>>(x, bfrags, ypatch);
        gather_kernel<<<(nPix / 4 + 255) / 256, 256, 0, stream>>>(ypatch, out);
    } else {
        hipMemsetAsync(d_out, 0, (size_t)out_size * sizeof(float), stream);
        conv_mfma_kernel<1><<<BN_ * C_ * 2, 512, 0, stream>>>(x, bfrags, out);
        divide_kernel<<<(nPix + 255) / 256, 256, 0, stream>>>(out);
    }
}

// Round 13
// 77.517 us; speedup vs baseline: 1.0428x; 1.0428x over previous
//
#include <hip/hip_runtime.h>
#include <math.h>

#define B_ 8
#define C_ 3
#define HW_ 512
#define P_ 128
#define S_ 64
#define K_ 31
#define NZ_ 15
#define HID_ 64
#define NPOS_ 49   // 7x7 patch positions
#define BN_ (B_*NPOS_)

#define LROWB_ 384     // bytes per LDS row (192 bf16); == 0 mod 128B -> XOR swizzle valid
#define TROWS_ 160     // 128 rows + 31 halo + 1 spare (tile row r <-> patch row r-16)
#define FRAG_U32_ 256
#define NSTEP_ 16      // jrow = 2s + (k>=16), jrow=0 masked (halo-16)
#define BPOS_U32_ (NSTEP_ * 3 * FRAG_U32_)  // 12288 uints per patch position

typedef __attribute__((ext_vector_type(8))) short bf16x8;
typedef __attribute__((ext_vector_type(4))) float f32x4;

__device__ __forceinline__ float hann128(int p) {
    return 0.5f - 0.5f * cosf(6.283185307179586f * (float)p / 128.0f);
}

__device__ __forceinline__ unsigned int bf16_rne(float f) {
    union { float f; unsigned int u; } v; v.f = f;
    unsigned int r = v.u + 0x7fffu + ((v.u >> 16) & 1u);
    return r >> 16;
}

__device__ __forceinline__ float bf16_to_f(unsigned int bits16) {
    union { unsigned int u; float f; } v; v.u = bits16 << 16;
    return v.f;
}

// ---------------------------------------------------------------------------
// Kernel 1: MLP + pupil + 31x31 DFT -> normalized flipped kernel -> row-pair
// B-fragment precompute (halo-16 convention). One block per position (49).
// Fragment (s, c), logical k in [0,32): jrow = 2s + (k>=16),
//   B_c[k][n] = kf[jrow-1, 16c + (k&15) - n - 1] if jrow,tap in 1..31 else 0.
// Lane labeling (matches conv A reads, empirically validated r4-r12):
//   lane l: n = l&15, k = (l>>4)*8 + e, e = 0..7.
// ---------------------------------------------------------------------------
__global__ __launch_bounds__(1024) void psf_kernel(
    const float* __restrict__ w1, const float* __restrict__ b1,
    const float* __restrict__ w2, const float* __restrict__ b2,
    const float* __restrict__ w3, const float* __restrict__ b3,
    const float* __restrict__ basis, unsigned int* __restrict__ bfrags)
{
    __shared__ float h1[HID_], h2[HID_], coef[NZ_];
    __shared__ float pupR[961], pupI[961], tR[961], tI[961];
    __shared__ float rootR[31], rootI[31];
    __shared__ float red[16];
    int n = blockIdx.x;
    int nh = n / 7, nw = n % 7;
    int tid = threadIdx.x;
    float cy = (float)(nh * S_ + P_ / 2) * (2.0f / (float)HW_) - 1.0f;
    float cx = (float)(nw * S_ + P_ / 2) * (2.0f / (float)HW_) - 1.0f;

    if (tid < HID_) h1[tid] = fmaxf(0.0f, cy * w1[tid] + cx * w1[HID_ + tid] + b1[tid]);
    if (tid < 31) {
        float ang = -6.283185307179586f * (float)tid / 31.0f;
        rootR[tid] = cosf(ang);
        rootI[tid] = sinf(ang);
    }
    __syncthreads();
    if (tid < HID_) {
        float s = b2[tid];
        for (int k = 0; k < HID_; ++k) s = fmaf(h1[k], w2[k * HID_ + tid], s);
        h2[tid] = fmaxf(0.0f, s);
    }
    __syncthreads();
    if (tid < NZ_) {
        float s = b3[tid];
        for (int k = 0; k < HID_; ++k) s = fmaf(h2[k], w3[k * NZ_ + tid], s);
        coef[tid] = s;
    }
    __syncthreads();

    for (int idx = tid; idx < 961; idx += 1024) {
        int h = idx / 31, w = idx % 31;
        float ph = 0.0f;
        for (int z = 0; z < NZ_; ++z) ph = fmaf(coef[z], basis[z * 961 + idx], ph);
        int dh = h - 15, dw = w - 15;
        bool m = (dh * dh + dw * dw) <= 225;
        float sv, cv;
        sincosf(ph, &sv, &cv);
        pupR[idx] = m ? cv : 0.0f;
        pupI[idx] = m ? sv : 0.0f;
    }
    __syncthreads();

    for (int idx = tid; idx < 961; idx += 1024) {
        int h = idx / 31, k = idx % 31;
        float ar = 0.0f, ai = 0.0f;
        for (int w = 0; w < 31; ++w) {
            int tt = (k * w) % 31;
            float cr = rootR[tt], ci = rootI[tt];
            float pr = pupR[h * 31 + w], pi = pupI[h * 31 + w];
            ar += pr * cr - pi * ci;
            ai += pr * ci + pi * cr;
        }
        tR[idx] = ar; tI[idx] = ai;
    }
    __syncthreads();

    float lsum = 0.0f;
    for (int idx = tid; idx < 961; idx += 1024) {
        int u = idx / 31, k = idx % 31;
        float gr = 0.0f, gi = 0.0f;
        for (int h = 0; h < 31; ++h) {
            int tt = (u * h) % 31;
            float cr = rootR[tt], ci = rootI[tt];
            float ar = tR[h * 31 + k], ai = tI[h * 31 + k];
            gr += ar * cr - ai * ci;
            gi += ar * ci + ai * cr;
        }
        float p = gr * gr + gi * gi;
        pupR[idx] = p;
        lsum += p;
    }
    float v = lsum;
    #pragma unroll
    for (int off = 32; off >= 1; off >>= 1) v += __shfl_xor(v, off, 64);
    if ((tid & 63) == 0) red[tid >> 6] = v;
    __syncthreads();
    if (tid == 0) {
        float s = 0.0f;
        #pragma unroll
        for (int i = 0; i < 16; ++i) s += red[i];
        red[0] = 1.0f / (s + 1e-12f);
    }
    __syncthreads();
    float inv = red[0];
    // kf[j,i] = psf_un[(15-j)%31, (15-i)%31] * inv  -> stash in tI (free now)
    for (int idx = tid; idx < 961; idx += 1024) {
        int j = idx / 31, i = idx % 31;
        int u = (15 - j + 31) % 31, vv = (15 - i + 31) % 31;
        tI[idx] = pupR[u * 31 + vv] * inv;
    }
    __syncthreads();

    unsigned int* bf = bfrags + (size_t)n * BPOS_U32_;
    for (int w2 = tid; w2 < BPOS_U32_; w2 += 1024) {
        int jc = w2 >> 8;            // 256 uints per fragment; jc = s*3 + c
        int s = jc / 3, c = jc % 3;
        int rem = w2 & 255;
        int l = rem >> 2, ew = rem & 3;
        int nn = l & 15, kg = l >> 4;
        unsigned int pack = 0;
        #pragma unroll
        for (int q = 0; q < 2; ++q) {
            int e = ew * 2 + q;
            int kk = kg * 8 + e;
            int jrow = 2 * s + (kk >> 4);          // halo-16: kernel row = jrow-1
            int tap = 16 * c + (kk & 15) - nn;     // halo-16: kernel col = tap-1
            float vx = (jrow >= 1 && jrow <= 31 && tap >= 1 && tap <= 31)
                       ? tI[(jrow - 1) * 31 + (tap - 1)] : 0.0f;
            pack |= bf16_rne(vx) << (16 * q);
        }
        bf[w2] = pack;
    }
}

// ---------------------------------------------------------------------------
// Kernel 2 (v13): row-pair banded bf16 MFMA GEMM, full-width waves + stagger.
// One block per (patch, channel): 128x128 out, 512 threads = 8 waves, each a
// 16-row x 128-col strip with acc[8]. LDS tile 160 rows x 384 B, XOR-swizzled
// (zero-conflict, measured r12). Per step: 10 ds_read_b128 A-windows (shared
// across the 8 col-chunks) + 3 B loads + 24 MFMA. Waves process the 16 steps
// in rotated order (ss = (s + 2*wv) & 15) -> LDS bursts of different waves
// interleave with other waves' MFMA phases (no convoy).
// ---------------------------------------------------------------------------
template<int MODE>
__global__ __launch_bounds__(512, 4) void conv_mfma_kernel(
    const float* __restrict__ x, const unsigned int* __restrict__ bfrags,
    void* __restrict__ dst)
{
    __shared__ unsigned short sIn[TROWS_ * (LROWB_ / 2)];   // 160*384 = 61440 B
    __shared__ float sH[128];

    int t = blockIdx.x;
    int cc = t % 3;
    int bn = t / 3;
    int b = bn / NPOS_, n = bn % NPOS_;
    int nh = n / 7, nw = n % 7;
    int r0 = nh * S_, c0 = nw * S_;
    int tid = threadIdx.x;

    if (tid < 128) sH[tid] = hann128(tid);

    // zero-fill tile (halo + spare stay zero); linear, conflict-free
    for (int i = tid; i < TROWS_ * LROWB_ / 16; i += 512)
        ((uint4*)sIn)[i] = make_uint4(0u, 0u, 0u, 0u);
    __syncthreads();

    // stage interior, swizzled uint4 writes:
    // tile row r <-> patch row r-16 (r = 16..143); tile col 16+c <-> patch col c
    const float* xb = x + ((size_t)(b * C_ + cc) * HW_ + r0) * HW_ + c0;
    for (int i = tid; i < 128 * 16; i += 512) {
        int r = 16 + (i >> 4), c8 = (i & 15) * 8;   // patch cols c8..c8+7
        const float* rp = &xb[(r - 16) * HW_ + c8];
        float4 v0 = *(const float4*)rp;
        float4 v1 = *(const float4*)(rp + 4);
        uint4 o;
        o.x = bf16_rne(v0.x) | (bf16_rne(v0.y) << 16);
        o.y = bf16_rne(v0.z) | (bf16_rne(v0.w) << 16);
        o.z = bf16_rne(v1.x) | (bf16_rne(v1.y) << 16);
        o.w = bf16_rne(v1.z) | (bf16_rne(v1.w) << 16);
        int byteoff = (r * LROWB_ + 32 + c8 * 2) ^ ((r & 7) << 4);
        *(uint4*)((char*)sIn + byteoff) = o;
    }
    __syncthreads();

    int lane = tid & 63, wv = tid >> 6;
    int m0 = wv * 16;              // wave's 16-row strip
    int lrow = lane & 15, lkg = lane >> 4;

    f32x4 acc[8];
    #pragma unroll
    for (int q = 0; q < 8; ++q) acc[q] = (f32x4){0.f, 0.f, 0.f, 0.f};

    int rowb = m0 + lrow + (lkg >> 1);   // A tile-row at step ss: rowb + 2*ss
    int colb = (lkg & 1) * 16;           // byte col offset
    const bf16x8* bpos = (const bf16x8*)(bfrags + (size_t)n * BPOS_U32_) + lane;
    int sbase = wv * 2;                  // per-wave step rotation

    // B prefetch for first step
    int ss0 = sbase & 15;
    bf16x8 Bc0 = bpos[ss0 * 192], Bc1 = bpos[ss0 * 192 + 64], Bc2 = bpos[ss0 * 192 + 128];

    #pragma unroll 2
    for (int s = 0; s < NSTEP_; ++s) {
        int ss = (s + sbase) & 15;
        bf16x8 Bn0, Bn1, Bn2;
        if (s + 1 < NSTEP_) {
            int ssn = (s + 1 + sbase) & 15;
            const bf16x8* bp = bpos + ssn * 192;
            Bn0 = bp[0]; Bn1 = bp[64]; Bn2 = bp[128];
        } else { Bn0 = Bc0; Bn1 = Bc1; Bn2 = Bc2; }

        int r2 = rowb + 2 * ss;
        int base = r2 * LROWB_ + colb;
        int xorv = (r2 & 7) << 4;
        bf16x8 A[10];
        #pragma unroll
        for (int p = 0; p < 10; ++p)
            A[p] = *(const bf16x8*)((const char*)sIn + ((base + p * 32) ^ xorv));

        __builtin_amdgcn_s_setprio(1);
        #pragma unroll
        for (int q = 0; q < 8; ++q) {
            acc[q] = __builtin_amdgcn_mfma_f32_16x16x32_bf16(A[q],     Bc0, acc[q], 0, 0, 0);
            acc[q] = __builtin_amdgcn_mfma_f32_16x16x32_bf16(A[q + 1], Bc1, acc[q], 0, 0, 0);
            acc[q] = __builtin_amdgcn_mfma_f32_16x16x32_bf16(A[q + 2], Bc2, acc[q], 0, 0, 0);
        }
        __builtin_amdgcn_s_setprio(0);
        Bc0 = Bn0; Bc1 = Bn1; Bc2 = Bn2;
    }

    // epilogue: C/D layout col = lane&15, row = lkg*4 + r (m89-verified)
    int prow0 = m0 + lkg * 4;
    float hy[4];
    #pragma unroll
    for (int r = 0; r < 4; ++r) hy[r] = sH[prow0 + r];

    #pragma unroll
    for (int q = 0; q < 8; ++q) {
        int pcol = 16 * q + lrow;
        float hxv = sH[pcol];
        #pragma unroll
        for (int r = 0; r < 4; ++r) {
            int prow = prow0 + r;
            float val = acc[q][r] * hy[r] * hxv;
            if (MODE == 0) {
                unsigned short* yp = (unsigned short*)dst + (((size_t)bn * C_ + cc) << 14);
                yp[prow * P_ + pcol] = (unsigned short)bf16_rne(val);
            } else {
                float* ob = (float*)dst;
                atomicAdd(ob + ((size_t)(b * C_ + cc) * HW_ + r0 + prow) * HW_ + c0 + pcol, val);
            }
        }
    }
}

// ---------------------------------------------------------------------------
// Kernel 3a: gather overlap-add (x4 vectorized, bf16 patches), analytic divide
// ---------------------------------------------------------------------------
__global__ __launch_bounds__(256) void gather_kernel(
    const unsigned short* __restrict__ ypatch, float* __restrict__ out)
{
    __shared__ float sH[128];
    int tid = threadIdx.x;
    if (tid < 128) sH[tid] = hann128(tid);
    __syncthreads();

    int gid = blockIdx.x * 256 + tid;
    int base = gid * 4;
    if (base >= B_ * C_ * HW_ * HW_) return;
    int X = base & 511;
    int Y = (base >> 9) & 511;
    int bc = base >> 18;
    int c = bc % 3, b = bc / 3;
    int nhA = Y >> 6, pyA = Y & 63;
    int nwA = X >> 6, pxA = X & 63;       // multiple of 4
    bool vA = nhA <= 6, vB = nhA >= 1;
    bool uA = nwA <= 6, uB = nwA >= 1;
    float wy = (vA ? sH[pyA] : 0.0f) + (vB ? sH[pyA + 64] : 0.0f);

    float4 acc = {0.f, 0.f, 0.f, 0.f};
    #pragma unroll
    for (int sy = 0; sy < 2; ++sy) {
        bool okY = sy == 0 ? vA : vB;
        int nh = sy == 0 ? nhA : nhA - 1;
        int py = sy == 0 ? pyA : pyA + 64;
        #pragma unroll
        for (int sx = 0; sx < 2; ++sx) {
            bool okX = sx == 0 ? uA : uB;
            int nw = sx == 0 ? nwA : nwA - 1;
            int px = sx == 0 ? pxA : pxA + 64;
            if (okY && okX) {
                size_t off = ((((size_t)b * NPOS_ + nh * 7 + nw) * C_ + c) << 14) + (py << 7) + px;
                uint2 v = *(const uint2*)&ypatch[off];
                acc.x += bf16_to_f(v.x & 0xffffu);
                acc.y += bf16_to_f(v.x >> 16);
                acc.z += bf16_to_f(v.y & 0xffffu);
                acc.w += bf16_to_f(v.y >> 16);
            }
        }
    }
    float4 o;
    float wx0 = (uA ? sH[pxA + 0] : 0.0f) + (uB ? sH[pxA + 64] : 0.0f);
    float wx1 = (uA ? sH[pxA + 1] : 0.0f) + (uB ? sH[pxA + 65] : 0.0f);
    float wx2 = (uA ? sH[pxA + 2] : 0.0f) + (uB ? sH[pxA + 66] : 0.0f);
    float wx3 = (uA ? sH[pxA + 3] : 0.0f) + (uB ? sH[pxA + 67] : 0.0f);
    o.x = acc.x / (wy * wx0 + 1e-8f);
    o.y = acc.y / (wy * wx1 + 1e-8f);
    o.z = acc.z / (wy * wx2 + 1e-8f);
    o.w = acc.w / (wy * wx3 + 1e-8f);
    *(float4*)&out[base] = o;
}

// ---------------------------------------------------------------------------
// Kernel 3b: in-place divide (atomic fallback path)
// ---------------------------------------------------------------------------
__global__ __launch_bounds__(256) void divide_kernel(float* __restrict__ out)
{
    int idx = blockIdx.x * 256 + threadIdx.x;
    if (idx >= B_ * C_ * HW_ * HW_) return;
    int X = idx & 511;
    int Y = (idx >> 9) & 511;
    int nhA = Y >> 6, pyA = Y & 63;
    int nwA = X >> 6, pxA = X & 63;
    float wy = (nhA <= 6 ? hann128(pyA) : 0.0f) + (nhA >= 1 ? hann128(pyA + 64) : 0.0f);
    float wx = (nwA <= 6 ? hann128(pxA) : 0.0f) + (nwA >= 1 ? hann128(pxA + 64) : 0.0f);
    out[idx] = out[idx] / (wy * wx + 1e-8f);
}

extern "C" void kernel_launch(void* const* d_in, const int* in_sizes, int n_in,
                              void* d_out, int out_size, void* d_ws, size_t ws_size,
                              hipStream_t stream)
{
    const float* x    = (const float*)d_in[0];
    const float* w1   = (const float*)d_in[1];
    const float* b1   = (const float*)d_in[2];
    const float* w2   = (const float*)d_in[3];
    const float* b2   = (const float*)d_in[4];
    const float* w3   = (const float*)d_in[5];
    const float* b3   = (const float*)d_in[6];
    const float* basis = (const float*)d_in[7];
    float* out = (float*)d_out;

    unsigned int* bfrags = (unsigned int*)d_ws;
    size_t bfBytes = (size_t)NPOS_ * BPOS_U32_ * sizeof(unsigned int);            // ~2.41 MB
    size_t need = bfBytes + (size_t)BN_ * C_ * P_ * P_ * sizeof(unsigned short);  // + 38.5 MB

    psf_kernel<<<NPOS_, 1024, 0, stream>>>(w1, b1, w2, b2, w3, b3, basis, bfrags);

    int nPix = B_ * C_ * HW_ * HW_;
    if (ws_size >= need) {
        unsigned short* ypatch = (unsigned short*)((char*)d_ws + bfBytes);
        conv_mfma_kernel<0><<<BN_ * C_, 512, 0, stream>>>(x, bfrags, ypatch);
        gather_kernel<<<(nPix / 4 + 255) / 256, 256, 0, stream>>>(ypatch, out);
    } else {
        hipMemsetAsync(d_out, 0, (size_t)out_size * sizeof(float), stream);
        conv_mfma_kernel<1><<<BN_ * C_, 512, 0, stream>>>(x, bfrags, out);
        divide_kernel<<<(nPix + 255) / 256, 256, 0, stream>>>(out);
    }
}